// Round 1
// baseline (183.040 us; speedup 1.0000x reference)
//
#include <hip/hip_runtime.h>
#include <math.h>

#define B_N 512
#define D_N 768
#define R_N 128
#define ALPHA 2.0f
#define BETA 50.0f
#define BASE 0.5f
#define EPS_M 0.1f
#define NB 16

// ---------------- Kernel A: bucket rows by relation ----------------
__global__ void k_bucket(const int* __restrict__ re_id, int* __restrict__ cnt,
                         int* __restrict__ members) {
    int tid = threadIdx.x;  // 512 threads, 1 block
    if (tid < R_N) cnt[tid] = 0;
    __syncthreads();
    int r = re_id[tid];
    int k = atomicAdd(&cnt[r], 1);
    members[r * B_N + k] = tid;
}

// ---------------- Kernel B: grouped matvec t[b] = M[re_id[b]] @ x[b] --------
// grid (128 relations, 6 i-tiles of 128 rows), block 256
__global__ __launch_bounds__(256) void k_matvec(
    const float* __restrict__ transform, const float* __restrict__ cui0,
    const int* __restrict__ cnt, const int* __restrict__ members,
    float* __restrict__ t_out) {
    int r = blockIdx.x;
    int tile = blockIdx.y * 128;
    int n = cnt[r];
    if (n == 0) return;

    __shared__ float xs[NB][D_N];  // 48 KiB
    int tid = threadIdx.x;
    int lane = tid & 63;
    int w = tid >> 6;

    const float* Mbase = transform + (size_t)r * (D_N * (size_t)D_N);

    for (int cs = 0; cs < n; cs += NB) {
        int nc = min(NB, n - cs);
        __syncthreads();  // previous chunk's compute done before overwrite
        // stage nc x-vectors into LDS (float4)
        for (int cb = 0; cb < nc; ++cb) {
            int b = members[r * B_N + cs + cb];
            if (tid < 192) {
                ((float4*)xs[cb])[tid] =
                    ((const float4*)(cui0 + (size_t)b * D_N))[tid];
            }
        }
        __syncthreads();

        for (int ii = w; ii < 128; ii += 4) {
            int i = tile + ii;
            const float4* Mrow = (const float4*)(Mbase + (size_t)i * D_N);
            float4 m0 = Mrow[lane];
            float4 m1 = Mrow[64 + lane];
            float4 m2 = Mrow[128 + lane];
#pragma unroll
            for (int cb = 0; cb < NB; ++cb) {
                if (cb < nc) {
                    const float4* xr = (const float4*)xs[cb];
                    float4 x0 = xr[lane];
                    float4 x1 = xr[64 + lane];
                    float4 x2 = xr[128 + lane];
                    float acc = m0.x * x0.x + m0.y * x0.y + m0.z * x0.z + m0.w * x0.w
                              + m1.x * x1.x + m1.y * x1.y + m1.z * x1.z + m1.w * x1.w
                              + m2.x * x2.x + m2.y * x2.y + m2.z * x2.z + m2.w * x2.w;
#pragma unroll
                    for (int off = 32; off > 0; off >>= 1)
                        acc += __shfl_down(acc, off, 64);
                    if (lane == 0) {
                        int b = members[r * B_N + cs + cb];
                        t_out[(size_t)b * D_N + i] = acc;
                    }
                }
            }
        }
    }
}

// ---------------- Kernel C: inverse row norms ----------------
// 1024 waves: first 512 rows of t, next 512 rows of cui1. grid 256 x 256thr
__global__ __launch_bounds__(256) void k_norms(
    const float* __restrict__ t_in, const float* __restrict__ cui1,
    float* __restrict__ inv_t, float* __restrict__ inv_c) {
    int gw = blockIdx.x * 4 + (threadIdx.x >> 6);
    int lane = threadIdx.x & 63;
    const float* src = (gw < B_N) ? (t_in + (size_t)gw * D_N)
                                  : (cui1 + (size_t)(gw - B_N) * D_N);
    const float4* s4 = (const float4*)src;
    float s = 0.f;
#pragma unroll
    for (int c = 0; c < 3; ++c) {
        float4 v = s4[c * 64 + lane];
        s += v.x * v.x + v.y * v.y + v.z * v.z + v.w * v.w;
    }
#pragma unroll
    for (int off = 32; off > 0; off >>= 1) s += __shfl_down(s, off, 64);
    if (lane == 0) {
        float nrm = sqrtf(s);
        float inv = 1.0f / fmaxf(nrm, 1e-12f);
        if (gw < B_N) inv_t[gw] = inv;
        else inv_c[gw - B_N] = inv;
    }
}

// ---------------- Kernel D: mat = norm(t) @ norm(cui1)^T ----------------
// 32x32 tile per block; grid (16,16), block 256
__global__ __launch_bounds__(256) void k_gemm(
    const float* __restrict__ t_in, const float* __restrict__ cui1,
    const float* __restrict__ inv_t, const float* __restrict__ inv_c,
    float* __restrict__ mat) {
    __shared__ float At[32][33];
    __shared__ float Bt[32][33];
    int row0 = blockIdx.y * 32, col0 = blockIdx.x * 32;
    int tid = threadIdx.x;
    int tx = tid & 15, ty = tid >> 4;
    float acc00 = 0.f, acc01 = 0.f, acc10 = 0.f, acc11 = 0.f;

    for (int k0 = 0; k0 < D_N; k0 += 32) {
        __syncthreads();
#pragma unroll
        for (int p = 0; p < 4; ++p) {
            int idx = tid + p * 256;
            int rr = idx >> 5, kk = idx & 31;
            At[rr][kk] = t_in[(size_t)(row0 + rr) * D_N + k0 + kk] * inv_t[row0 + rr];
            Bt[rr][kk] = cui1[(size_t)(col0 + rr) * D_N + k0 + kk] * inv_c[col0 + rr];
        }
        __syncthreads();
#pragma unroll
        for (int kk = 0; kk < 32; ++kk) {
            float a0 = At[2 * ty][kk], a1 = At[2 * ty + 1][kk];
            float b0 = Bt[2 * tx][kk], b1 = Bt[2 * tx + 1][kk];
            acc00 += a0 * b0; acc01 += a0 * b1;
            acc10 += a1 * b0; acc11 += a1 * b1;
        }
    }
    int rb = row0 + 2 * ty, cb = col0 + 2 * tx;
    mat[(size_t)rb * B_N + cb]           = acc00;
    mat[(size_t)rb * B_N + cb + 1]       = acc01;
    mat[(size_t)(rb + 1) * B_N + cb]     = acc10;
    mat[(size_t)(rb + 1) * B_N + cb + 1] = acc11;
}

// ---------------- Kernel E: miner + MS loss per row ----------------
// one block (256 thr) per row; each thread handles 2 columns
__global__ __launch_bounds__(256) void k_loss(
    const float* __restrict__ mat, const int* __restrict__ lab,
    float* __restrict__ row_loss) {
    int r = blockIdx.x;
    int tid = threadIdx.x;
    int lane = tid & 63, w = tid >> 6;
    __shared__ float tmp[4];
    int lr = lab[r];
    const float* mrow = mat + (size_t)r * B_N;

    float v0 = mrow[tid], v1 = mrow[tid + 256];
    bool m0 = (lab[tid] == lr), m1 = (lab[tid + 256] == lr);

    float mx = -INFINITY, mn = INFINITY;
    if (m0) mn = v0; else mx = v0;
    if (m1) mn = fminf(mn, v1); else mx = fmaxf(mx, v1);

#pragma unroll
    for (int off = 32; off > 0; off >>= 1) mx = fmaxf(mx, __shfl_xor(mx, off, 64));
    if (lane == 0) tmp[w] = mx;
    __syncthreads();
    float max_neg = fmaxf(fmaxf(tmp[0], tmp[1]), fmaxf(tmp[2], tmp[3]));
    __syncthreads();

#pragma unroll
    for (int off = 32; off > 0; off >>= 1) mn = fminf(mn, __shfl_xor(mn, off, 64));
    if (lane == 0) tmp[w] = mn;
    __syncthreads();
    float min_pos = fminf(fminf(tmp[0], tmp[1]), fminf(tmp[2], tmp[3]));
    __syncthreads();

    float psum = 0.f, nsum = 0.f;
    if (m0 && (v0 - EPS_M < max_neg)) psum += expf(ALPHA * (BASE - v0));
    if (!m0 && (v0 + EPS_M > min_pos)) nsum += expf(BETA * (v0 - BASE));
    if (m1 && (v1 - EPS_M < max_neg)) psum += expf(ALPHA * (BASE - v1));
    if (!m1 && (v1 + EPS_M > min_pos)) nsum += expf(BETA * (v1 - BASE));

#pragma unroll
    for (int off = 32; off > 0; off >>= 1) psum += __shfl_xor(psum, off, 64);
    if (lane == 0) tmp[w] = psum;
    __syncthreads();
    float ps = tmp[0] + tmp[1] + tmp[2] + tmp[3];
    __syncthreads();

#pragma unroll
    for (int off = 32; off > 0; off >>= 1) nsum += __shfl_xor(nsum, off, 64);
    if (lane == 0) tmp[w] = nsum;
    __syncthreads();
    float ns = tmp[0] + tmp[1] + tmp[2] + tmp[3];

    if (tid == 0)
        row_loss[r] = (1.0f / ALPHA) * log1pf(ps) + (1.0f / BETA) * log1pf(ns);
}

// ---------------- Kernel F: mean ----------------
__global__ void k_mean(const float* __restrict__ row_loss, float* __restrict__ out) {
    int tid = threadIdx.x;  // 512 threads
    float v = row_loss[tid];
    __shared__ float tmp[8];
#pragma unroll
    for (int off = 32; off > 0; off >>= 1) v += __shfl_down(v, off, 64);
    if ((tid & 63) == 0) tmp[tid >> 6] = v;
    __syncthreads();
    if (tid == 0) {
        float s = 0.f;
        for (int i = 0; i < 8; ++i) s += tmp[i];
        out[0] = s / (float)B_N;
    }
}

extern "C" void kernel_launch(void* const* d_in, const int* in_sizes, int n_in,
                              void* d_out, int out_size, void* d_ws, size_t ws_size,
                              hipStream_t stream) {
    const float* cui0      = (const float*)d_in[0];
    const float* cui1      = (const float*)d_in[1];
    const int*   re_id     = (const int*)d_in[2];
    const int*   lab1      = (const int*)d_in[4];
    const float* transform = (const float*)d_in[5];
    float* out = (float*)d_out;

    float* ws = (float*)d_ws;
    float* t        = ws;                    // 512*768
    float* inv_t    = t + (size_t)B_N * D_N; // 512
    float* inv_c    = inv_t + B_N;           // 512
    float* mat      = inv_c + B_N;           // 512*512
    float* row_loss = mat + (size_t)B_N * B_N; // 512
    int*   cnt      = (int*)(row_loss + B_N);  // 128
    int*   members  = cnt + R_N;               // 128*512

    hipLaunchKernelGGL(k_bucket, dim3(1), dim3(B_N), 0, stream, re_id, cnt, members);
    hipLaunchKernelGGL(k_matvec, dim3(R_N, 6), dim3(256), 0, stream,
                       transform, cui0, cnt, members, t);
    hipLaunchKernelGGL(k_norms, dim3(256), dim3(256), 0, stream, t, cui1, inv_t, inv_c);
    hipLaunchKernelGGL(k_gemm, dim3(16, 16), dim3(256), 0, stream,
                       t, cui1, inv_t, inv_c, mat);
    hipLaunchKernelGGL(k_loss, dim3(B_N), dim3(256), 0, stream, mat, lab1, row_loss);
    hipLaunchKernelGGL(k_mean, dim3(1), dim3(B_N), 0, stream, row_loss, out);
}

// Round 2
// 110.371 us; speedup vs baseline: 1.6584x; 1.6584x over previous
//
#include <hip/hip_runtime.h>
#include <math.h>

#define B_N 512
#define D_N 768
#define R_N 128
#define ALPHA 2.0f
#define BETA 50.0f
#define BASE 0.5f
#define EPS_M 0.1f
#define NB 8

// ---------------- Kernel A: bucket rows by relation ----------------
__global__ void k_bucket(const int* __restrict__ re_id, int* __restrict__ cnt,
                         int* __restrict__ members) {
    int tid = threadIdx.x;  // 512 threads, 1 block
    if (tid < R_N) cnt[tid] = 0;
    __syncthreads();
    int r = re_id[tid];
    int k = atomicAdd(&cnt[r], 1);
    members[r * B_N + k] = tid;
}

// ---------------- Kernel B: grouped matvec t[b] = M[re_id[b]] @ x[b] --------
// grid (128 relations, 12 tiles of 64 rows), block 256.
// One wave handles 4 M-rows at a time: 16 lanes per row, 12 float4/lane.
__global__ __launch_bounds__(256, 4) void k_matvec(
    const float* __restrict__ transform, const float* __restrict__ cui0,
    const int* __restrict__ cnt, const int* __restrict__ members,
    float* __restrict__ t_out) {
    int r = blockIdx.x;
    int n = cnt[r];
    if (n == 0) return;
    int tile = blockIdx.y * 64;

    __shared__ float xs[NB][D_N];  // 24 KiB
    __shared__ int bs[NB];
    int tid = threadIdx.x;
    int lane = tid & 63;
    int w = tid >> 6;
    int g = lane >> 4;    // which of 4 rows in the unit
    int l16 = lane & 15;  // k-slot within the row

    const float* Mbase = transform + (size_t)r * ((size_t)D_N * D_N);
    const int* mrow = members + r * B_N;

    for (int cs = 0; cs < n; cs += NB) {
        int nc = min(NB, n - cs);
        __syncthreads();  // previous chunk done before overwrite
        if (tid < nc) bs[tid] = mrow[cs + tid];
        for (int idx = tid; idx < nc * 192; idx += 256) {
            int cb = idx / 192, pos = idx - cb * 192;
            int b = mrow[cs + cb];
            ((float4*)xs[cb])[pos] = ((const float4*)(cui0 + (size_t)b * D_N))[pos];
        }
        __syncthreads();

        // 4 units of 4 rows per wave -> 64 rows per block
        for (int uu = 0; uu < 4; ++uu) {
            int i = tile + (w + 4 * uu) * 4 + g;
            const float4* Mrow4 = (const float4*)(Mbase + (size_t)i * D_N);
            float4 m[12];
#pragma unroll
            for (int c = 0; c < 12; ++c) m[c] = Mrow4[l16 + 16 * c];
            for (int cb = 0; cb < nc; ++cb) {
                const float4* xr = (const float4*)xs[cb];
                float acc = 0.f;
#pragma unroll
                for (int c = 0; c < 12; ++c) {
                    float4 x = xr[l16 + 16 * c];
                    acc += m[c].x * x.x + m[c].y * x.y + m[c].z * x.z + m[c].w * x.w;
                }
                // reduce across the 16 lanes of this row (4 rows in parallel)
                acc += __shfl_xor(acc, 8, 64);
                acc += __shfl_xor(acc, 4, 64);
                acc += __shfl_xor(acc, 2, 64);
                acc += __shfl_xor(acc, 1, 64);
                if (l16 == 0) {
                    t_out[(size_t)bs[cb] * D_N + i] = acc;
                }
            }
        }
    }
}

// ---------------- Kernel C: inverse row norms ----------------
// 1024 waves: first 512 rows of t, next 512 rows of cui1. grid 256 x 256thr
__global__ __launch_bounds__(256) void k_norms(
    const float* __restrict__ t_in, const float* __restrict__ cui1,
    float* __restrict__ inv_t, float* __restrict__ inv_c) {
    int gw = blockIdx.x * 4 + (threadIdx.x >> 6);
    int lane = threadIdx.x & 63;
    const float* src = (gw < B_N) ? (t_in + (size_t)gw * D_N)
                                  : (cui1 + (size_t)(gw - B_N) * D_N);
    const float4* s4 = (const float4*)src;
    float s = 0.f;
#pragma unroll
    for (int c = 0; c < 3; ++c) {
        float4 v = s4[c * 64 + lane];
        s += v.x * v.x + v.y * v.y + v.z * v.z + v.w * v.w;
    }
#pragma unroll
    for (int off = 32; off > 0; off >>= 1) s += __shfl_down(s, off, 64);
    if (lane == 0) {
        float nrm = sqrtf(s);
        float inv = 1.0f / fmaxf(nrm, 1e-12f);
        if (gw < B_N) inv_t[gw] = inv;
        else inv_c[gw - B_N] = inv;
    }
}

// ---------------- Kernel D: mat = norm(t) @ norm(cui1)^T ----------------
// 32x32 tile per block; grid (16,16), block 256
__global__ __launch_bounds__(256) void k_gemm(
    const float* __restrict__ t_in, const float* __restrict__ cui1,
    const float* __restrict__ inv_t, const float* __restrict__ inv_c,
    float* __restrict__ mat) {
    __shared__ float At[32][33];
    __shared__ float Bt[32][33];
    int row0 = blockIdx.y * 32, col0 = blockIdx.x * 32;
    int tid = threadIdx.x;
    int tx = tid & 15, ty = tid >> 4;
    float acc00 = 0.f, acc01 = 0.f, acc10 = 0.f, acc11 = 0.f;

    for (int k0 = 0; k0 < D_N; k0 += 32) {
        __syncthreads();
#pragma unroll
        for (int p = 0; p < 4; ++p) {
            int idx = tid + p * 256;
            int rr = idx >> 5, kk = idx & 31;
            At[rr][kk] = t_in[(size_t)(row0 + rr) * D_N + k0 + kk] * inv_t[row0 + rr];
            Bt[rr][kk] = cui1[(size_t)(col0 + rr) * D_N + k0 + kk] * inv_c[col0 + rr];
        }
        __syncthreads();
#pragma unroll
        for (int kk = 0; kk < 32; ++kk) {
            float a0 = At[2 * ty][kk], a1 = At[2 * ty + 1][kk];
            float b0 = Bt[2 * tx][kk], b1 = Bt[2 * tx + 1][kk];
            acc00 += a0 * b0; acc01 += a0 * b1;
            acc10 += a1 * b0; acc11 += a1 * b1;
        }
    }
    int rb = row0 + 2 * ty, cb = col0 + 2 * tx;
    mat[(size_t)rb * B_N + cb]           = acc00;
    mat[(size_t)rb * B_N + cb + 1]       = acc01;
    mat[(size_t)(rb + 1) * B_N + cb]     = acc10;
    mat[(size_t)(rb + 1) * B_N + cb + 1] = acc11;
}

// ---------------- Kernel E: miner + MS loss per row ----------------
// one block (256 thr) per row; each thread handles 2 columns
__global__ __launch_bounds__(256) void k_loss(
    const float* __restrict__ mat, const int* __restrict__ lab,
    float* __restrict__ row_loss) {
    int r = blockIdx.x;
    int tid = threadIdx.x;
    int lane = tid & 63, w = tid >> 6;
    __shared__ float tmp[4];
    int lr = lab[r];
    const float* mrow = mat + (size_t)r * B_N;

    float v0 = mrow[tid], v1 = mrow[tid + 256];
    bool m0 = (lab[tid] == lr), m1 = (lab[tid + 256] == lr);

    float mx = -INFINITY, mn = INFINITY;
    if (m0) mn = v0; else mx = v0;
    if (m1) mn = fminf(mn, v1); else mx = fmaxf(mx, v1);

#pragma unroll
    for (int off = 32; off > 0; off >>= 1) mx = fmaxf(mx, __shfl_xor(mx, off, 64));
    if (lane == 0) tmp[w] = mx;
    __syncthreads();
    float max_neg = fmaxf(fmaxf(tmp[0], tmp[1]), fmaxf(tmp[2], tmp[3]));
    __syncthreads();

#pragma unroll
    for (int off = 32; off > 0; off >>= 1) mn = fminf(mn, __shfl_xor(mn, off, 64));
    if (lane == 0) tmp[w] = mn;
    __syncthreads();
    float min_pos = fminf(fminf(tmp[0], tmp[1]), fminf(tmp[2], tmp[3]));
    __syncthreads();

    float psum = 0.f, nsum = 0.f;
    if (m0 && (v0 - EPS_M < max_neg)) psum += expf(ALPHA * (BASE - v0));
    if (!m0 && (v0 + EPS_M > min_pos)) nsum += expf(BETA * (v0 - BASE));
    if (m1 && (v1 - EPS_M < max_neg)) psum += expf(ALPHA * (BASE - v1));
    if (!m1 && (v1 + EPS_M > min_pos)) nsum += expf(BETA * (v1 - BASE));

#pragma unroll
    for (int off = 32; off > 0; off >>= 1) psum += __shfl_xor(psum, off, 64);
    if (lane == 0) tmp[w] = psum;
    __syncthreads();
    float ps = tmp[0] + tmp[1] + tmp[2] + tmp[3];
    __syncthreads();

#pragma unroll
    for (int off = 32; off > 0; off >>= 1) nsum += __shfl_xor(nsum, off, 64);
    if (lane == 0) tmp[w] = nsum;
    __syncthreads();
    float ns = tmp[0] + tmp[1] + tmp[2] + tmp[3];

    if (tid == 0)
        row_loss[r] = (1.0f / ALPHA) * log1pf(ps) + (1.0f / BETA) * log1pf(ns);
}

// ---------------- Kernel F: mean ----------------
__global__ void k_mean(const float* __restrict__ row_loss, float* __restrict__ out) {
    int tid = threadIdx.x;  // 512 threads
    float v = row_loss[tid];
    __shared__ float tmp[8];
#pragma unroll
    for (int off = 32; off > 0; off >>= 1) v += __shfl_down(v, off, 64);
    if ((tid & 63) == 0) tmp[tid >> 6] = v;
    __syncthreads();
    if (tid == 0) {
        float s = 0.f;
        for (int i = 0; i < 8; ++i) s += tmp[i];
        out[0] = s / (float)B_N;
    }
}

extern "C" void kernel_launch(void* const* d_in, const int* in_sizes, int n_in,
                              void* d_out, int out_size, void* d_ws, size_t ws_size,
                              hipStream_t stream) {
    const float* cui0      = (const float*)d_in[0];
    const float* cui1      = (const float*)d_in[1];
    const int*   re_id     = (const int*)d_in[2];
    const int*   lab1      = (const int*)d_in[4];
    const float* transform = (const float*)d_in[5];
    float* out = (float*)d_out;

    float* ws = (float*)d_ws;
    float* t        = ws;                    // 512*768
    float* inv_t    = t + (size_t)B_N * D_N; // 512
    float* inv_c    = inv_t + B_N;           // 512
    float* mat      = inv_c + B_N;           // 512*512
    float* row_loss = mat + (size_t)B_N * B_N; // 512
    int*   cnt      = (int*)(row_loss + B_N);  // 128
    int*   members  = cnt + R_N;               // 128*512

    hipLaunchKernelGGL(k_bucket, dim3(1), dim3(B_N), 0, stream, re_id, cnt, members);
    hipLaunchKernelGGL(k_matvec, dim3(R_N, 12), dim3(256), 0, stream,
                       transform, cui0, cnt, members, t);
    hipLaunchKernelGGL(k_norms, dim3(256), dim3(256), 0, stream, t, cui1, inv_t, inv_c);
    hipLaunchKernelGGL(k_gemm, dim3(16, 16), dim3(256), 0, stream,
                       t, cui1, inv_t, inv_c, mat);
    hipLaunchKernelGGL(k_loss, dim3(B_N), dim3(256), 0, stream, mat, lab1, row_loss);
    hipLaunchKernelGGL(k_mean, dim3(1), dim3(B_N), 0, stream, row_loss, out);
}

// Round 3
// 86.316 us; speedup vs baseline: 2.1206x; 1.2787x over previous
//
#include <hip/hip_runtime.h>
#include <math.h>

#define B_N 512
#define D_N 768
#define R_N 128
#define ALPHA 2.0f
#define BETA 50.0f
#define BASE 0.5f
#define EPS_M 0.1f
#define NB 8
#define KS 32
#define KCH 192  // 768 / 4 K-chunks

// ---------------- Kernel A: bucket rows by relation ----------------
__global__ void k_bucket(const int* __restrict__ re_id, int* __restrict__ cnt,
                         int* __restrict__ members) {
    int tid = threadIdx.x;  // 512 threads, 1 block
    if (tid < R_N) cnt[tid] = 0;
    __syncthreads();
    int r = re_id[tid];
    int k = atomicAdd(&cnt[r], 1);
    members[r * B_N + k] = tid;
}

// ---------------- Kernel B: grouped matvec t[b] = M[re_id[b]] @ x[b] --------
// grid (128 relations, 24 tiles of 32 rows), block 256.
// Each wave holds 2 units of 4 M-rows in registers (16 lanes per row).
__global__ __launch_bounds__(256, 3) void k_matvec(
    const float* __restrict__ transform, const float* __restrict__ cui0,
    const int* __restrict__ cnt, const int* __restrict__ members,
    float* __restrict__ t_out) {
    int r = blockIdx.x;
    int n = cnt[r];
    if (n == 0) return;
    int tile = blockIdx.y * 32;

    __shared__ float xs[NB][D_N];  // 24 KiB
    __shared__ int bs[NB];
    int tid = threadIdx.x;
    int lane = tid & 63;
    int w = tid >> 6;
    int g = lane >> 4;    // which of 4 rows in a unit
    int l16 = lane & 15;  // k-slot within the row

    const float* Mbase = transform + (size_t)r * ((size_t)D_N * D_N);
    const int* mrow = members + r * B_N;

    // rows owned by this wave: unit0 = tile + w*8 + g, unit1 = tile + w*8 + 4 + g
    int i0 = tile + w * 8 + g;
    int i1 = i0 + 4;
    const float4* M0 = (const float4*)(Mbase + (size_t)i0 * D_N);
    const float4* M1 = (const float4*)(Mbase + (size_t)i1 * D_N);
    float4 m0[12], m1[12];
#pragma unroll
    for (int c = 0; c < 12; ++c) m0[c] = M0[l16 + 16 * c];
#pragma unroll
    for (int c = 0; c < 12; ++c) m1[c] = M1[l16 + 16 * c];

    for (int cs = 0; cs < n; cs += NB) {
        int nc = min(NB, n - cs);
        __syncthreads();  // previous chunk done before overwrite
        if (tid < nc) bs[tid] = mrow[cs + tid];
        for (int idx = tid; idx < nc * 192; idx += 256) {
            int cb = idx / 192, pos = idx - cb * 192;
            int b = mrow[cs + cb];
            ((float4*)xs[cb])[pos] = ((const float4*)(cui0 + (size_t)b * D_N))[pos];
        }
        __syncthreads();

        for (int cb = 0; cb < nc; ++cb) {
            const float4* xr = (const float4*)xs[cb];
            float a0 = 0.f, a1 = 0.f;
#pragma unroll
            for (int c = 0; c < 12; ++c) {
                float4 x = xr[l16 + 16 * c];
                a0 += m0[c].x * x.x + m0[c].y * x.y + m0[c].z * x.z + m0[c].w * x.w;
                a1 += m1[c].x * x.x + m1[c].y * x.y + m1[c].z * x.z + m1[c].w * x.w;
            }
            a0 += __shfl_xor(a0, 8, 64);
            a1 += __shfl_xor(a1, 8, 64);
            a0 += __shfl_xor(a0, 4, 64);
            a1 += __shfl_xor(a1, 4, 64);
            a0 += __shfl_xor(a0, 2, 64);
            a1 += __shfl_xor(a1, 2, 64);
            a0 += __shfl_xor(a0, 1, 64);
            a1 += __shfl_xor(a1, 1, 64);
            if (l16 == 0) {
                size_t ob = (size_t)bs[cb] * D_N;
                t_out[ob + i0] = a0;
                t_out[ob + i1] = a1;
            }
        }
    }
}

// ---------------- Kernel C: inverse row norms ----------------
__global__ __launch_bounds__(256) void k_norms(
    const float* __restrict__ t_in, const float* __restrict__ cui1,
    float* __restrict__ inv_t, float* __restrict__ inv_c) {
    int gw = blockIdx.x * 4 + (threadIdx.x >> 6);
    int lane = threadIdx.x & 63;
    const float* src = (gw < B_N) ? (t_in + (size_t)gw * D_N)
                                  : (cui1 + (size_t)(gw - B_N) * D_N);
    const float4* s4 = (const float4*)src;
    float s = 0.f;
#pragma unroll
    for (int c = 0; c < 3; ++c) {
        float4 v = s4[c * 64 + lane];
        s += v.x * v.x + v.y * v.y + v.z * v.z + v.w * v.w;
    }
#pragma unroll
    for (int off = 32; off > 0; off >>= 1) s += __shfl_down(s, off, 64);
    if (lane == 0) {
        float nrm = sqrtf(s);
        float inv = 1.0f / fmaxf(nrm, 1e-12f);
        if (gw < B_N) inv_t[gw] = inv;
        else inv_c[gw - B_N] = inv;
    }
}

// ---------------- Kernel D: partial GEMM mat_z = A_z @ B_z^T ----------------
// 64x64 tile, 4x4 micro, transposed LDS, K split 4 ways via blockIdx.z.
// grid (8, 8, 4), block 256.
__global__ __launch_bounds__(256) void k_gemm(
    const float* __restrict__ t_in, const float* __restrict__ cui1,
    const float* __restrict__ inv_t, const float* __restrict__ inv_c,
    float* __restrict__ part) {
    __shared__ float At[KS][68];  // [kk][row], pad 68 keeps 16B align + bank spread
    __shared__ float Bt[KS][68];
    int row0 = blockIdx.y * 64, col0 = blockIdx.x * 64;
    int kbase = blockIdx.z * KCH;
    int tid = threadIdx.x;
    int tx = tid & 15, ty = tid >> 4;
    int rr = tid >> 2, gg = tid & 3;  // staging map
    float ia = inv_t[row0 + rr];
    float ib = inv_c[col0 + rr];
    float acc[4][4] = {};

    for (int ks = 0; ks < KCH; ks += KS) {
        int k0 = kbase + ks;
        __syncthreads();
#pragma unroll
        for (int h = 0; h < 2; ++h) {
            int kg = gg + 4 * h;  // float4 group 0..7 within KS
            float4 a = *(const float4*)&t_in[(size_t)(row0 + rr) * D_N + k0 + kg * 4];
            float4 b = *(const float4*)&cui1[(size_t)(col0 + rr) * D_N + k0 + kg * 4];
            At[kg * 4 + 0][rr] = a.x * ia;
            At[kg * 4 + 1][rr] = a.y * ia;
            At[kg * 4 + 2][rr] = a.z * ia;
            At[kg * 4 + 3][rr] = a.w * ia;
            Bt[kg * 4 + 0][rr] = b.x * ib;
            Bt[kg * 4 + 1][rr] = b.y * ib;
            Bt[kg * 4 + 2][rr] = b.z * ib;
            Bt[kg * 4 + 3][rr] = b.w * ib;
        }
        __syncthreads();
#pragma unroll
        for (int kk = 0; kk < KS; ++kk) {
            float4 av = *(const float4*)&At[kk][4 * ty];
            float4 bv = *(const float4*)&Bt[kk][4 * tx];
            float as[4] = {av.x, av.y, av.z, av.w};
            float bsv[4] = {bv.x, bv.y, bv.z, bv.w};
#pragma unroll
            for (int i = 0; i < 4; ++i)
#pragma unroll
                for (int j = 0; j < 4; ++j) acc[i][j] += as[i] * bsv[j];
        }
    }
    float* pz = part + (size_t)blockIdx.z * B_N * B_N;
#pragma unroll
    for (int i = 0; i < 4; ++i) {
        float4 v = make_float4(acc[i][0], acc[i][1], acc[i][2], acc[i][3]);
        *(float4*)&pz[(size_t)(row0 + 4 * ty + i) * B_N + col0 + 4 * tx] = v;
    }
}

// ---------------- Kernel E: miner + MS loss per row ----------------
// one block (256 thr) per row; sums the 4 K-partials on load
__global__ __launch_bounds__(256) void k_loss(
    const float* __restrict__ part, const int* __restrict__ lab,
    float* __restrict__ row_loss) {
    const int N2 = B_N * B_N;
    int r = blockIdx.x;
    int tid = threadIdx.x;
    int lane = tid & 63, w = tid >> 6;
    __shared__ float tmp[4];
    int lr = lab[r];
    size_t base = (size_t)r * B_N;

    float v0 = part[base + tid] + part[N2 + base + tid] +
               part[2 * N2 + base + tid] + part[3 * N2 + base + tid];
    int c1 = tid + 256;
    float v1 = part[base + c1] + part[N2 + base + c1] +
               part[2 * N2 + base + c1] + part[3 * N2 + base + c1];
    bool m0 = (lab[tid] == lr), m1 = (lab[c1] == lr);

    float mx = -INFINITY, mn = INFINITY;
    if (m0) mn = v0; else mx = v0;
    if (m1) mn = fminf(mn, v1); else mx = fmaxf(mx, v1);

#pragma unroll
    for (int off = 32; off > 0; off >>= 1) mx = fmaxf(mx, __shfl_xor(mx, off, 64));
    if (lane == 0) tmp[w] = mx;
    __syncthreads();
    float max_neg = fmaxf(fmaxf(tmp[0], tmp[1]), fmaxf(tmp[2], tmp[3]));
    __syncthreads();

#pragma unroll
    for (int off = 32; off > 0; off >>= 1) mn = fminf(mn, __shfl_xor(mn, off, 64));
    if (lane == 0) tmp[w] = mn;
    __syncthreads();
    float min_pos = fminf(fminf(tmp[0], tmp[1]), fminf(tmp[2], tmp[3]));
    __syncthreads();

    float psum = 0.f, nsum = 0.f;
    if (m0 && (v0 - EPS_M < max_neg)) psum += expf(ALPHA * (BASE - v0));
    if (!m0 && (v0 + EPS_M > min_pos)) nsum += expf(BETA * (v0 - BASE));
    if (m1 && (v1 - EPS_M < max_neg)) psum += expf(ALPHA * (BASE - v1));
    if (!m1 && (v1 + EPS_M > min_pos)) nsum += expf(BETA * (v1 - BASE));

#pragma unroll
    for (int off = 32; off > 0; off >>= 1) psum += __shfl_xor(psum, off, 64);
    if (lane == 0) tmp[w] = psum;
    __syncthreads();
    float ps = tmp[0] + tmp[1] + tmp[2] + tmp[3];
    __syncthreads();

#pragma unroll
    for (int off = 32; off > 0; off >>= 1) nsum += __shfl_xor(nsum, off, 64);
    if (lane == 0) tmp[w] = nsum;
    __syncthreads();
    float ns = tmp[0] + tmp[1] + tmp[2] + tmp[3];

    if (tid == 0)
        row_loss[r] = (1.0f / ALPHA) * log1pf(ps) + (1.0f / BETA) * log1pf(ns);
}

// ---------------- Kernel F: mean ----------------
__global__ void k_mean(const float* __restrict__ row_loss, float* __restrict__ out) {
    int tid = threadIdx.x;  // 512 threads
    float v = row_loss[tid];
    __shared__ float tmp[8];
#pragma unroll
    for (int off = 32; off > 0; off >>= 1) v += __shfl_down(v, off, 64);
    if ((tid & 63) == 0) tmp[tid >> 6] = v;
    __syncthreads();
    if (tid == 0) {
        float s = 0.f;
        for (int i = 0; i < 8; ++i) s += tmp[i];
        out[0] = s / (float)B_N;
    }
}

extern "C" void kernel_launch(void* const* d_in, const int* in_sizes, int n_in,
                              void* d_out, int out_size, void* d_ws, size_t ws_size,
                              hipStream_t stream) {
    const float* cui0      = (const float*)d_in[0];
    const float* cui1      = (const float*)d_in[1];
    const int*   re_id     = (const int*)d_in[2];
    const int*   lab1      = (const int*)d_in[4];
    const float* transform = (const float*)d_in[5];
    float* out = (float*)d_out;

    float* ws = (float*)d_ws;
    float* t        = ws;                        // 512*768
    float* inv_t    = t + (size_t)B_N * D_N;     // 512
    float* inv_c    = inv_t + B_N;               // 512
    float* part     = inv_c + B_N;               // 4*512*512
    float* row_loss = part + 4 * (size_t)B_N * B_N;  // 512
    int*   cnt      = (int*)(row_loss + B_N);    // 128
    int*   members  = cnt + R_N;                 // 128*512

    hipLaunchKernelGGL(k_bucket, dim3(1), dim3(B_N), 0, stream, re_id, cnt, members);
    hipLaunchKernelGGL(k_matvec, dim3(R_N, 24), dim3(256), 0, stream,
                       transform, cui0, cnt, members, t);
    hipLaunchKernelGGL(k_norms, dim3(256), dim3(256), 0, stream, t, cui1, inv_t, inv_c);
    hipLaunchKernelGGL(k_gemm, dim3(8, 8, 4), dim3(256), 0, stream,
                       t, cui1, inv_t, inv_c, part);
    hipLaunchKernelGGL(k_loss, dim3(B_N), dim3(256), 0, stream, part, lab1, row_loss);
    hipLaunchKernelGGL(k_mean, dim3(1), dim3(B_N), 0, stream, row_loss, out);
}